// Round 3
// baseline (279.342 us; speedup 1.0000x reference)
//
#include <hip/hip_runtime.h>
#include <math.h>
#include <cstddef>

// Shapes fixed by setup_inputs()
#define B_  16
#define T2_ 2048
#define T1_ 512
#define F_  128

constexpr float DELTA_C  = 10.0f;
constexpr float EPS_C    = 1e-8f;
constexpr float THRESH_C = 0.9f;
constexpr float STEEP_C  = 10.0f;

typedef float f4v __attribute__((ext_vector_type(4)));

// Fused single-launch pipeline: 1024 blocks x 256 threads, whole grid co-resident
// (__launch_bounds__(256,4) -> 4 blocks/CU -> 1024 = 4 x 256CU, the sanctioned
// capacity pattern). Batch b owned by blocks [b*64, b*64+64).
//   phase A: each block streams 32 alpha rows (activity + imv_proposal),
//            then agent-release atomicAdd(done_act[b]).
//   phase B: block (g&63)==0 spins for done_act[b]==64 (relaxed poll + one
//            agent-acquire fence), runs the per-batch scan, release-stores
//            scan_done[b].
//   phase C: every wave pools one phoneme-pair of its batch after observing
//            scan_done[b] (agent-acquire).
// Flags live in ws (re-poisoned each iter) -> zeroed by a 128B hipMemsetAsync.
__global__ __launch_bounds__(256, 4) void fused_kernel(
        const float* __restrict__ mels,
        const float* __restrict__ alpha,
        const int* __restrict__ mel_mask,
        const int* __restrict__ text_mask,
        float* __restrict__ act,
        float* __restrict__ prop,
        float* __restrict__ imv_out,
        float2* __restrict__ packed,
        int2* __restrict__ bounds,
        float* __restrict__ aligned,
        float* __restrict__ dur,
        int* done_act,
        int* scan_done)
{
    __shared__ float s_imv[T2_];       // scan keys (phase B only)
    __shared__ float s_wsum[4];
    __shared__ int   s_am4[4], s_tm4[4];
    __shared__ int   s_tm[T1_];

    const int g    = blockIdx.x;
    const int b    = g >> 6;           // 64 blocks per batch
    const int tid  = threadIdx.x;
    const int wv   = tid >> 6, lane = tid & 63;
    const int il   = lane & 15, sub = lane >> 4;

    // ---------------- phase A: activity + imv_proposal (32 rows/block) -----
    #pragma unroll
    for (int p = 0; p < 2; ++p) {
        int r = g * 32 + p * 16 + wv * 4 + sub;   // rows don't cross batches
        int t = r & (T2_ - 1);

        const f4v* arow = (const f4v*)(alpha + (size_t)r * T1_);
        f4v a0 = __builtin_nontemporal_load(&arow[il]);
        f4v a1 = __builtin_nontemporal_load(&arow[il + 16]);
        f4v a2 = __builtin_nontemporal_load(&arow[il + 32]);
        f4v a3 = __builtin_nontemporal_load(&arow[il + 48]);
        f4v a4 = __builtin_nontemporal_load(&arow[il + 64]);
        f4v a5 = __builtin_nontemporal_load(&arow[il + 80]);
        f4v a6 = __builtin_nontemporal_load(&arow[il + 96]);
        f4v a7 = __builtin_nontemporal_load(&arow[il + 112]);

        int rm = (t == 0) ? r : (r - 1);
        const f4v* my = (const f4v*)(mels + (size_t)r  * F_);
        const f4v* mx = (const f4v*)(mels + (size_t)rm * F_);
        f4v y0 = my[il * 2], y1 = my[il * 2 + 1];
        f4v x0 = mx[il * 2], x1 = mx[il * 2 + 1];

        float d  = x0.x*y0.x + x0.y*y0.y + x0.z*y0.z + x0.w*y0.w
                 + x1.x*y1.x + x1.y*y1.y + x1.z*y1.z + x1.w*y1.w;
        float n0 = x0.x*x0.x + x0.y*x0.y + x0.z*x0.z + x0.w*x0.w
                 + x1.x*x1.x + x1.y*x1.y + x1.z*x1.z + x1.w*x1.w;
        float n1 = y0.x*y0.x + y0.y*y0.y + y0.z*y0.z + y0.w*y0.w
                 + y1.x*y1.x + y1.y*y1.y + y1.z*y1.z + y1.w*y1.w;

        float fb = (float)(il * 4);
        float psum;
        psum  = a0.x*(fb      ) + a0.y*(fb +   1.f) + a0.z*(fb +   2.f) + a0.w*(fb +   3.f);
        psum += a1.x*(fb+ 64.f) + a1.y*(fb +  65.f) + a1.z*(fb +  66.f) + a1.w*(fb +  67.f);
        psum += a2.x*(fb+128.f) + a2.y*(fb + 129.f) + a2.z*(fb + 130.f) + a2.w*(fb + 131.f);
        psum += a3.x*(fb+192.f) + a3.y*(fb + 193.f) + a3.z*(fb + 194.f) + a3.w*(fb + 195.f);
        psum += a4.x*(fb+256.f) + a4.y*(fb + 257.f) + a4.z*(fb + 258.f) + a4.w*(fb + 259.f);
        psum += a5.x*(fb+320.f) + a5.y*(fb + 321.f) + a5.z*(fb + 322.f) + a5.w*(fb + 323.f);
        psum += a6.x*(fb+384.f) + a6.y*(fb + 385.f) + a6.z*(fb + 386.f) + a6.w*(fb + 387.f);
        psum += a7.x*(fb+448.f) + a7.y*(fb + 449.f) + a7.z*(fb + 450.f) + a7.w*(fb + 451.f);

        // 16-lane group reduction (xor 8,4,2,1 stays within the group)
        for (int off = 8; off > 0; off >>= 1) {
            psum += __shfl_xor(psum, off, 64);
            d    += __shfl_xor(d,    off, 64);
            n0   += __shfl_xor(n0,   off, 64);
            n1   += __shfl_xor(n1,   off, 64);
        }

        if (il == 0) {
            float a_val;
            if (t == 0) {
                a_val = 1.0f;
            } else {
                float cs = d / (fmaxf(sqrtf(n0), 1e-12f) * fmaxf(sqrtf(n1), 1e-12f));
                a_val = 1.0f / (1.0f + __expf(-STEEP_C * (THRESH_C - cs)));
            }
            act[r]  = a_val * (float)mel_mask[r];
            prop[r] = psum;
        }
    }
    __syncthreads();    // drains all waves' stores (vmcnt 0 before barrier)
    if (tid == 0)
        __hip_atomic_fetch_add(&done_act[b], 1, __ATOMIC_RELEASE, __HIP_MEMORY_SCOPE_AGENT);

    const bool is_scan = ((g & 63) == 0);

    // ---------------- phase B: per-batch scan (one block per batch) --------
    if (is_scan) {
        const int* tm = text_mask + (size_t)b * T1_;
        int tmv0 = tm[tid], tmv1 = tm[tid + 256];
        s_tm[tid] = tmv0; s_tm[tid + 256] = tmv1;

        if (lane == 0) {
            while (__hip_atomic_load(&done_act[b], __ATOMIC_RELAXED, __HIP_MEMORY_SCOPE_AGENT) < 64)
                __builtin_amdgcn_s_sleep(2);
        }
        __builtin_amdgcn_fence(__ATOMIC_ACQUIRE, "agent");
        __syncthreads();                                // B0

        const float* pr_ = prop + (size_t)b * T2_;
        const float* ac_ = act  + (size_t)b * T2_;
        const int*   mm_ = mel_mask + (size_t)b * T2_;

        float e[8];
        int   mmv[8];
        int t0 = tid * 8;
        int am_local = 0;
        float run = 0.0f;
        #pragma unroll
        for (int i = 0; i < 8; i++) {
            int t = t0 + i;
            float dd = (t == 0) ? 0.0f : (pr_[t] - pr_[t - 1]) * ac_[t];
            dd = fminf(fmaxf(dd, 0.0f), 1.0f);
            run += dd;
            e[i] = run;
            mmv[i] = mm_[t];
            am_local += mmv[i];
        }
        int tm_local = tmv0 + tmv1;
        for (int off = 32; off > 0; off >>= 1) {
            am_local += __shfl_xor(am_local, off, 64);
            tm_local += __shfl_xor(tm_local, off, 64);
        }
        if (lane == 0) { s_am4[wv] = am_local; s_tm4[wv] = tm_local; }

        float v = run;
        for (int off = 1; off < 64; off <<= 1) {
            float u = __shfl_up(v, off, 64);
            if (lane >= off) v += u;
        }
        if (lane == 63) s_wsum[wv] = v;
        __syncthreads();                                // B1

        float woff = 0.0f;
        for (int w = 0; w < 4; w++) woff += (w < wv) ? s_wsum[w] : 0.0f;
        float excl = woff + v - run;
        #pragma unroll
        for (int i = 0; i < 8; i++) {
            int t = t0 + i;
            s_imv[t] = (e[i] + excl) * (float)mmv[i];
        }
        __syncthreads();                                // B2

        int am_total = s_am4[0] + s_am4[1] + s_am4[2] + s_am4[3];
        int tm_total = s_tm4[0] + s_tm4[1] + s_tm4[2] + s_tm4[3];
        int last_idx = max(am_total - 1, 0);
        float last_val = fmaxf(s_imv[last_idx], 1e-6f);
        float scale = fmaxf((float)tm_total - 1.0f, 0.0f) / last_val;
        __syncthreads();                                // B3

        #pragma unroll
        for (int i = 0; i < 8; i++) {
            int t = t0 + i;
            int valid = mmv[i];
            float vv = s_imv[t] * scale * (float)valid;
            imv_out[(size_t)b * T2_ + t] = vv;
            // softmax denominator: 6-term band around floor(vv); excluded < 1e-39
            int c = (int)floorf(vv);
            float Z = 0.0f;
            for (int s = c - 2; s <= c + 3; s++) {
                if (s >= 0 && s < T1_ && s_tm[s]) {
                    float dd = vv - (float)s;
                    Z += __expf(-DELTA_C * dd * dd);
                }
            }
            Z = fmaxf(Z, 1e-30f);
            float key = valid ? vv : 3.0e4f;            // monotone past masked tail
            float2 pkv = {key, valid ? (1.0f / Z) : 0.0f};
            packed[(size_t)b * T2_ + t] = pkv;
            s_imv[t] = key;
        }
        __syncthreads();                                // B4

        // per-phoneme band bounds via binary search on monotone keys
        for (int k = 0; k < 2; k++) {
            int s = tid + k * 256;
            float lov = (float)s - 3.0f, hiv = (float)s + 3.0f;
            int lo = 0, hi = T2_;
            while (lo < hi) { int mid = (lo + hi) >> 1; if (s_imv[mid] >= lov) hi = mid; else lo = mid + 1; }
            int st = lo;
            hi = T2_;
            while (lo < hi) { int mid = (lo + hi) >> 1; if (s_imv[mid] > hiv) hi = mid; else lo = mid + 1; }
            int2 be = {st, lo};
            bounds[(size_t)b * T1_ + s] = be;
        }
        __syncthreads();    // drain packed/bounds stores before release
        if (tid == 0)
            __hip_atomic_store(&scan_done[b], 1, __ATOMIC_RELEASE, __HIP_MEMORY_SCOPE_AGENT);
        // own block's phase C reads its own writes (visible via __syncthreads)
    } else {
        if (lane == 0) {
            while (__hip_atomic_load(&scan_done[b], __ATOMIC_RELAXED, __HIP_MEMORY_SCOPE_AGENT) == 0)
                __builtin_amdgcn_s_sleep(2);
        }
        __builtin_amdgcn_fence(__ATOMIC_ACQUIRE, "agent");
    }

    // ---------------- phase C: pool (one phoneme-pair per wave) ------------
    {
        int pairi = (g & 63) * 4 + wv;   // 256 pairs per batch
        int s0 = pairi * 2;
        int half = lane >> 5, hl = lane & 31;
        float fs0 = (float)s0, fs1 = fs0 + 1.0f;

        const float2* pk   = packed + (size_t)b * T2_;
        const f4v*    mel4 = (const f4v*)(mels + (size_t)b * T2_ * F_);
        int2 b0 = bounds[(size_t)b * T1_ + s0];
        int2 b1 = bounds[(size_t)b * T1_ + s0 + 1];
        int t_lo = b0.x, t_hi = b1.y;    // covers both bands (monotone)

        float ax0 = 0.f, ay0 = 0.f, az0 = 0.f, aw0 = 0.f, g0s = 0.f;
        float ax1 = 0.f, ay1 = 0.f, az1 = 0.f, aw1 = 0.f, g1s = 0.f;
        for (int t = t_lo; t < t_hi; t += 2) {
            int  tl = t + half;              // half0 -> t, half1 -> t+1
            bool on = tl < t_hi;
            int  ts = on ? tl : t;           // safe in-band index
            float2 p = pk[ts];
            f4v    m = mel4[(size_t)ts * 32 + hl];
            float d0 = p.x - fs0, d1 = p.x - fs1;
            float g0 = on ? __expf(-DELTA_C * d0 * d0) * p.y : 0.0f;
            float g1 = on ? __expf(-DELTA_C * d1 * d1) * p.y : 0.0f;
            g0s += g0; g1s += g1;
            ax0 += g0 * m.x; ay0 += g0 * m.y; az0 += g0 * m.z; aw0 += g0 * m.w;
            ax1 += g1 * m.x; ay1 += g1 * m.y; az1 += g1 * m.z; aw1 += g1 * m.w;
        }

        g0s += __shfl_xor(g0s, 32, 64);
        g1s += __shfl_xor(g1s, 32, 64);
        ax0 += __shfl_xor(ax0, 32, 64);
        ay0 += __shfl_xor(ay0, 32, 64);
        az0 += __shfl_xor(az0, 32, 64);
        aw0 += __shfl_xor(aw0, 32, 64);
        ax1 += __shfl_xor(ax1, 32, 64);
        ay1 += __shfl_xor(ay1, 32, 64);
        az1 += __shfl_xor(az1, 32, 64);
        aw1 += __shfl_xor(aw1, 32, 64);

        float tm0 = (float)text_mask[(size_t)b * T1_ + s0];
        float tm1 = (float)text_mask[(size_t)b * T1_ + s0 + 1];
        float inv0 = tm0 / (g0s + EPS_C);
        float inv1 = tm1 / (g1s + EPS_C);

        f4v outv;
        if (half == 0) {
            outv.x = ax0 * inv0; outv.y = ay0 * inv0; outv.z = az0 * inv0; outv.w = aw0 * inv0;
        } else {
            outv.x = ax1 * inv1; outv.y = ay1 * inv1; outv.z = az1 * inv1; outv.w = aw1 * inv1;
        }
        float* obase = aligned + ((size_t)b * T1_ + s0 + half) * F_;
        ((f4v*)obase)[hl] = outv;
        if (lane == 0)  dur[(size_t)b * T1_ + s0]     = g0s * tm0;
        if (lane == 32) dur[(size_t)b * T1_ + s0 + 1] = g1s * tm1;
    }
}

extern "C" void kernel_launch(void* const* d_in, const int* in_sizes, int n_in,
                              void* d_out, int out_size, void* d_ws, size_t ws_size,
                              hipStream_t stream) {
    const float* mels      = (const float*)d_in[0];
    const float* alpha     = (const float*)d_in[1];
    const int*   mel_mask  = (const int*)d_in[2];
    const int*   text_mask = (const int*)d_in[3];

    float* out     = (float*)d_out;
    float* aligned = out;                                   // B*T1*F
    float* dur     = out + (size_t)B_ * T1_ * F_;           // B*T1
    float* imv     = dur + (size_t)B_ * T1_;                // B*T2

    float*  ws     = (float*)d_ws;
    float*  act    = ws;                                    // B*T2
    float*  prop   = ws + (size_t)B_ * T2_;                 // B*T2
    float2* packed = (float2*)(ws + 2 * (size_t)B_ * T2_);  // B*T2 float2
    int2*   bounds = (int2*)(ws + 4 * (size_t)B_ * T2_);    // B*T1 int2
    int*    flags  = (int*)((char*)d_ws + (1 << 20));       // 1 MiB offset, 128 B

    // flags region is re-poisoned each iteration -> zero it (capture-safe)
    hipMemsetAsync(flags, 0, 32 * sizeof(int), stream);

    fused_kernel<<<1024, dim3(256), 0, stream>>>(mels, alpha, mel_mask, text_mask,
                                                 act, prop, imv, packed, bounds,
                                                 aligned, dur, flags, flags + 16);
}

// Round 5
// 128.108 us; speedup vs baseline: 2.1805x; 2.1805x over previous
//
#include <hip/hip_runtime.h>
#include <math.h>
#include <cstddef>

// Shapes fixed by setup_inputs()
#define B_  16
#define T2_ 2048
#define T1_ 512
#define F_  128

constexpr float DELTA_C  = 10.0f;
constexpr float EPS_C    = 1e-8f;
constexpr float THRESH_C = 0.9f;
constexpr float STEEP_C  = 10.0f;

typedef float f4v __attribute__((ext_vector_type(4)));

// --- K1 (fused): activity + imv_proposal.
// 4 rows per wave, 16 lanes per row. Reduction is 4 butterfly levels
// shared across rows -> 4 DS ops/row instead of 24; per-row overhead /4.
// alpha streamed once -> nontemporal keeps it out of L2 (mels stays cached).
__global__ __launch_bounds__(256) void actprop_kernel(const float* __restrict__ mels,
                                                      const float* __restrict__ alpha,
                                                      const int* __restrict__ mel_mask,
                                                      float* __restrict__ act,
                                                      float* __restrict__ prop) {
    int wv   = (int)((blockIdx.x * blockDim.x + threadIdx.x) >> 6);
    int lane = threadIdx.x & 63;
    int il   = lane & 15;               // lane within 16-lane row group
    int r    = wv * 4 + (lane >> 4);    // grid sized exactly: r < B_*T2_
    int t    = r & (T2_ - 1);           // T2 is a power of two

    // alpha row: 512 floats = 128 f4v; 16 lanes x 8 chunks, 256B/row/instr
    const f4v* arow = (const f4v*)(alpha + (size_t)r * T1_);
    f4v a0 = __builtin_nontemporal_load(&arow[il]);
    f4v a1 = __builtin_nontemporal_load(&arow[il + 16]);
    f4v a2 = __builtin_nontemporal_load(&arow[il + 32]);
    f4v a3 = __builtin_nontemporal_load(&arow[il + 48]);
    f4v a4 = __builtin_nontemporal_load(&arow[il + 64]);
    f4v a5 = __builtin_nontemporal_load(&arow[il + 80]);
    f4v a6 = __builtin_nontemporal_load(&arow[il + 96]);
    f4v a7 = __builtin_nontemporal_load(&arow[il + 112]);

    // mels rows t and t-1 (t==0: load own row, result unused)
    int rm = (t == 0) ? r : (r - 1);
    const f4v* my = (const f4v*)(mels + (size_t)r  * F_);
    const f4v* mx = (const f4v*)(mels + (size_t)rm * F_);
    f4v y0 = my[il * 2], y1 = my[il * 2 + 1];
    f4v x0 = mx[il * 2], x1 = mx[il * 2 + 1];

    float d  = x0.x*y0.x + x0.y*y0.y + x0.z*y0.z + x0.w*y0.w
             + x1.x*y1.x + x1.y*y1.y + x1.z*y1.z + x1.w*y1.w;
    float n0 = x0.x*x0.x + x0.y*x0.y + x0.z*x0.z + x0.w*x0.w
             + x1.x*x1.x + x1.y*x1.y + x1.z*x1.z + x1.w*x1.w;
    float n1 = y0.x*y0.x + y0.y*y0.y + y0.z*y0.z + y0.w*y0.w
             + y1.x*y1.x + y1.y*y1.y + y1.z*y1.z + y1.w*y1.w;

    // psum = sum_s alpha[s]*s ; chunk c covers floats il*4 + 64c .. +3
    float fb = (float)(il * 4);
    float psum;
    psum  = a0.x*(fb      ) + a0.y*(fb +   1.f) + a0.z*(fb +   2.f) + a0.w*(fb +   3.f);
    psum += a1.x*(fb+ 64.f) + a1.y*(fb +  65.f) + a1.z*(fb +  66.f) + a1.w*(fb +  67.f);
    psum += a2.x*(fb+128.f) + a2.y*(fb + 129.f) + a2.z*(fb + 130.f) + a2.w*(fb + 131.f);
    psum += a3.x*(fb+192.f) + a3.y*(fb + 193.f) + a3.z*(fb + 194.f) + a3.w*(fb + 195.f);
    psum += a4.x*(fb+256.f) + a4.y*(fb + 257.f) + a4.z*(fb + 258.f) + a4.w*(fb + 259.f);
    psum += a5.x*(fb+320.f) + a5.y*(fb + 321.f) + a5.z*(fb + 322.f) + a5.w*(fb + 323.f);
    psum += a6.x*(fb+384.f) + a6.y*(fb + 385.f) + a6.z*(fb + 386.f) + a6.w*(fb + 387.f);
    psum += a7.x*(fb+448.f) + a7.y*(fb + 449.f) + a7.z*(fb + 450.f) + a7.w*(fb + 451.f);

    // 16-lane group reduction (xor 8,4,2,1 stays within the group)
    for (int off = 8; off > 0; off >>= 1) {
        psum += __shfl_xor(psum, off, 64);
        d    += __shfl_xor(d,    off, 64);
        n0   += __shfl_xor(n0,   off, 64);
        n1   += __shfl_xor(n1,   off, 64);
    }

    if (il == 0) {
        float a_val;
        if (t == 0) {
            a_val = 1.0f;
        } else {
            float cs = d / (fmaxf(sqrtf(n0), 1e-12f) * fmaxf(sqrtf(n1), 1e-12f));
            a_val = 1.0f / (1.0f + __expf(-STEEP_C * (THRESH_C - cs)));
        }
        act[r]  = a_val * (float)mel_mask[r];
        prop[r] = psum;
    }
}

// --- K2: per batch: eff_delta -> wave-shuffle scan -> rescale -> imv,
//     packed {key, am/Z}, and per-phoneme band bounds via LDS binary search.
// v4: vectorized global loads (f4v prop/act, int4 mask) + vector LDS/global
// stores -> ~4 VMEM instrs/thread instead of ~16 on a latency-bound kernel.
__global__ __launch_bounds__(512) void scan_kernel(const float* __restrict__ prop,
                                                   const float* __restrict__ act,
                                                   const int* __restrict__ mel_mask,
                                                   const int* __restrict__ text_mask,
                                                   float* __restrict__ imv_out,
                                                   float2* __restrict__ packed,
                                                   int2* __restrict__ bounds) {
    int b    = blockIdx.x;
    int tid  = threadIdx.x;            // 512 threads, 4 t's each
    int wave = tid >> 6, lane = tid & 63;
    __shared__ float s_imv[T2_];       // later overwritten with search keys
    __shared__ float s_wsum[8];
    __shared__ int   s_am8[8], s_tm8[8];
    __shared__ int   s_tm[T1_];

    const float* pr = prop + (size_t)b * T2_;
    const float* ac = act  + (size_t)b * T2_;
    const int*   mm = mel_mask  + (size_t)b * T2_;
    const int*   tm = text_mask + (size_t)b * T1_;

    int tmv = tm[tid];
    s_tm[tid] = tmv;

    int t0 = tid * 4;
    f4v  pv = *(const f4v*)(pr + t0);
    f4v  av = *(const f4v*)(ac + t0);
    int4 mv = *(const int4*)(mm + t0);
    float prm1 = (tid == 0) ? 0.0f : pr[t0 - 1];

    float d0 = (tid == 0) ? 0.0f : (pv.x - prm1) * av.x;
    float d1 = (pv.y - pv.x) * av.y;
    float d2 = (pv.z - pv.y) * av.z;
    float d3 = (pv.w - pv.z) * av.w;
    d0 = fminf(fmaxf(d0, 0.0f), 1.0f);
    d1 = fminf(fmaxf(d1, 0.0f), 1.0f);
    d2 = fminf(fmaxf(d2, 0.0f), 1.0f);
    d3 = fminf(fmaxf(d3, 0.0f), 1.0f);

    float e[4];
    int   mmv[4];
    e[0] = d0; e[1] = e[0] + d1; e[2] = e[1] + d2; e[3] = e[2] + d3;
    mmv[0] = mv.x; mmv[1] = mv.y; mmv[2] = mv.z; mmv[3] = mv.w;
    float run = e[3];
    int am_local = mv.x + mv.y + mv.z + mv.w;

    int tm_local = tmv;
    for (int off = 32; off > 0; off >>= 1) {
        am_local += __shfl_xor(am_local, off, 64);
        tm_local += __shfl_xor(tm_local, off, 64);
    }
    if (lane == 0) { s_am8[wave] = am_local; s_tm8[wave] = tm_local; }

    // wave-level inclusive scan of per-thread totals
    float v = run;
    for (int off = 1; off < 64; off <<= 1) {
        float u = __shfl_up(v, off, 64);
        if (lane >= off) v += u;
    }
    if (lane == 63) s_wsum[wave] = v;
    __syncthreads();                                    // B1

    float woff = 0.0f;
    for (int w = 0; w < 8; w++) woff += (w < wave) ? s_wsum[w] : 0.0f;
    float excl = woff + v - run;
    {
        f4v sv = { (e[0] + excl) * (float)mmv[0],
                   (e[1] + excl) * (float)mmv[1],
                   (e[2] + excl) * (float)mmv[2],
                   (e[3] + excl) * (float)mmv[3] };
        *(f4v*)(s_imv + t0) = sv;
    }
    __syncthreads();                                    // B2

    int am_total = 0, tm_total = 0;
    for (int w = 0; w < 8; w++) { am_total += s_am8[w]; tm_total += s_tm8[w]; }
    int last_idx = max(am_total - 1, 0);
    float last_val = fmaxf(s_imv[last_idx], 1e-6f);
    float scale = fmaxf((float)tm_total - 1.0f, 0.0f) / last_val;
    __syncthreads();                                    // B3 (everyone read last_val)

    f4v vvv, keyv, rv;
    #pragma unroll
    for (int i = 0; i < 4; i++) {
        int t = t0 + i;
        int valid = mmv[i];
        float vv = s_imv[t] * scale * (float)valid;
        vvv[i] = vv;
        // softmax denominator: 6-term band around floor(vv); excluded terms < 1e-39
        int c = (int)floorf(vv);
        float Z = 0.0f;
        for (int s = c - 2; s <= c + 3; s++) {
            if (s >= 0 && s < T1_ && s_tm[s]) {
                float dd = vv - (float)s;
                Z += __expf(-DELTA_C * dd * dd);
            }
        }
        Z = fmaxf(Z, 1e-30f);
        keyv[i] = valid ? vv : 3.0e4f;                  // monotone past masked tail
        rv[i]   = valid ? (1.0f / Z) : 0.0f;            // r = am/Z
    }
    *(f4v*)(imv_out + (size_t)b * T2_ + t0) = vvv;
    {
        f4v p01 = { keyv[0], rv[0], keyv[1], rv[1] };
        f4v p23 = { keyv[2], rv[2], keyv[3], rv[3] };
        f4v* pko = (f4v*)(packed + (size_t)b * T2_ + t0);
        pko[0] = p01;
        pko[1] = p23;
        f4v* sk = (f4v*)(s_imv + t0);
        *sk = keyv;                                     // key array for searches
    }
    __syncthreads();                                    // B4

    // per-phoneme band bounds: start = lower_bound(key >= s-3), end = upper_bound(key > s+3)
    {
        int s = tid;
        float lov = (float)s - 3.0f, hiv = (float)s + 3.0f;
        int lo = 0, hi = T2_;
        while (lo < hi) { int mid = (lo + hi) >> 1; if (s_imv[mid] >= lov) hi = mid; else lo = mid + 1; }
        int st = lo;
        hi = T2_;
        while (lo < hi) { int mid = (lo + hi) >> 1; if (s_imv[mid] > hiv) hi = mid; else lo = mid + 1; }
        int2 be = {st, lo};
        bounds[(size_t)b * T1_ + s] = be;
    }
}

// --- K3: one wave per 2 adjacent phonemes (bands overlap 5/6 -> halve loads).
// Wave split into two 32-lane halves, each owning one frame of a pair with
// float4 loads -> one contiguous 1KB VMEM instr + 2 wave-exps per 2 frames;
// 10-shuffle cross-half combine at the end.
// Out-of-band extra terms are exp(<-90) == 0 in fp32, so joint accumulation is exact.
__global__ __launch_bounds__(256) void pool_kernel(const float* __restrict__ mels,
                                                   const int* __restrict__ text_mask,
                                                   const float2* __restrict__ packed,
                                                   const int2* __restrict__ bounds,
                                                   float* __restrict__ aligned,
                                                   float* __restrict__ dur) {
    int wid  = (int)((blockIdx.x * blockDim.x + threadIdx.x) >> 6);
    int lane = threadIdx.x & 63;
    if (wid >= B_ * (T1_ / 2)) return;
    int b = wid >> 8, s0 = (wid & 255) * 2;
    int half = lane >> 5, hl = lane & 31;
    float fs0 = (float)s0, fs1 = fs0 + 1.0f;

    const float2* pk   = packed + (size_t)b * T2_;
    const f4v*    mel4 = (const f4v*)(mels + (size_t)b * T2_ * F_);
    int2 b0 = bounds[(size_t)b * T1_ + s0];
    int2 b1 = bounds[(size_t)b * T1_ + s0 + 1];
    int t_lo = b0.x, t_hi = b1.y;       // covers both bands (monotone)

    float ax0 = 0.f, ay0 = 0.f, az0 = 0.f, aw0 = 0.f, g0s = 0.f;
    float ax1 = 0.f, ay1 = 0.f, az1 = 0.f, aw1 = 0.f, g1s = 0.f;
    for (int t = t_lo; t < t_hi; t += 2) {
        int  tl = t + half;                 // half0 -> t, half1 -> t+1
        bool on = tl < t_hi;
        int  ts = on ? tl : t;              // safe in-band index
        float2 p = pk[ts];
        f4v    m = mel4[(size_t)ts * 32 + hl];
        float d0 = p.x - fs0, d1 = p.x - fs1;
        float g0 = on ? __expf(-DELTA_C * d0 * d0) * p.y : 0.0f;
        float g1 = on ? __expf(-DELTA_C * d1 * d1) * p.y : 0.0f;
        g0s += g0; g1s += g1;
        ax0 += g0 * m.x; ay0 += g0 * m.y; az0 += g0 * m.z; aw0 += g0 * m.w;
        ax1 += g1 * m.x; ay1 += g1 * m.y; az1 += g1 * m.z; aw1 += g1 * m.w;
    }

    // cross-half combine: both halves end with full sums
    g0s += __shfl_xor(g0s, 32, 64);
    g1s += __shfl_xor(g1s, 32, 64);
    ax0 += __shfl_xor(ax0, 32, 64);
    ay0 += __shfl_xor(ay0, 32, 64);
    az0 += __shfl_xor(az0, 32, 64);
    aw0 += __shfl_xor(aw0, 32, 64);
    ax1 += __shfl_xor(ax1, 32, 64);
    ay1 += __shfl_xor(ay1, 32, 64);
    az1 += __shfl_xor(az1, 32, 64);
    aw1 += __shfl_xor(aw1, 32, 64);

    float tm0 = (float)text_mask[(size_t)b * T1_ + s0];
    float tm1 = (float)text_mask[(size_t)b * T1_ + s0 + 1];
    float inv0 = tm0 / (g0s + EPS_C);
    float inv1 = tm1 / (g1s + EPS_C);

    // half0 writes phoneme s0, half1 writes s0+1: one contiguous 1KB store
    f4v out;
    if (half == 0) {
        out.x = ax0 * inv0; out.y = ay0 * inv0; out.z = az0 * inv0; out.w = aw0 * inv0;
    } else {
        out.x = ax1 * inv1; out.y = ay1 * inv1; out.z = az1 * inv1; out.w = aw1 * inv1;
    }
    float* obase = aligned + ((size_t)b * T1_ + s0 + half) * F_;
    ((f4v*)obase)[hl] = out;
    if (lane == 0)  dur[(size_t)b * T1_ + s0]     = g0s * tm0;
    if (lane == 32) dur[(size_t)b * T1_ + s0 + 1] = g1s * tm1;
}

extern "C" void kernel_launch(void* const* d_in, const int* in_sizes, int n_in,
                              void* d_out, int out_size, void* d_ws, size_t ws_size,
                              hipStream_t stream) {
    const float* mels      = (const float*)d_in[0];
    const float* alpha     = (const float*)d_in[1];
    const int*   mel_mask  = (const int*)d_in[2];
    const int*   text_mask = (const int*)d_in[3];

    float* out     = (float*)d_out;
    float* aligned = out;                                   // B*T1*F
    float* dur     = out + (size_t)B_ * T1_ * F_;           // B*T1
    float* imv     = dur + (size_t)B_ * T1_;                // B*T2

    float*  ws     = (float*)d_ws;                          // 512 KB + 64 KB used
    float*  act    = ws;
    float*  prop   = ws + (size_t)B_ * T2_;
    float2* packed = (float2*)(ws + 2 * (size_t)B_ * T2_);
    int2*   bounds = (int2*)(ws + 4 * (size_t)B_ * T2_);

    actprop_kernel<<<(B_ * T2_) / 16, dim3(256), 0, stream>>>(mels, alpha, mel_mask, act, prop);
    scan_kernel   <<<B_,              dim3(512), 0, stream>>>(prop, act, mel_mask, text_mask, imv, packed, bounds);
    pool_kernel   <<<(B_ * T1_ / 2) / 4, dim3(256), 0, stream>>>(mels, text_mask, packed, bounds, aligned, dur);
}

// Round 8
// 128.095 us; speedup vs baseline: 2.1807x; 1.0001x over previous
//
#include <hip/hip_runtime.h>
#include <math.h>
#include <cstddef>

// Shapes fixed by setup_inputs()
#define B_  16
#define T2_ 2048
#define T1_ 512
#define F_  128

constexpr float DELTA_C  = 10.0f;
constexpr float EPS_C    = 1e-8f;
constexpr float THRESH_C = 0.9f;
constexpr float STEEP_C  = 10.0f;

typedef float f4v __attribute__((ext_vector_type(4)));

// --- K1 (fused): activity + imv_proposal.
// 4 rows per wave, 16 lanes per row. Reduction is 4 butterfly levels
// shared across rows; alpha streamed once (nontemporal).
__global__ __launch_bounds__(256) void actprop_kernel(const float* __restrict__ mels,
                                                      const float* __restrict__ alpha,
                                                      const int* __restrict__ mel_mask,
                                                      float* __restrict__ act,
                                                      float* __restrict__ prop) {
    int wv   = (int)((blockIdx.x * blockDim.x + threadIdx.x) >> 6);
    int lane = threadIdx.x & 63;
    int il   = lane & 15;               // lane within 16-lane row group
    int r    = wv * 4 + (lane >> 4);    // grid sized exactly: r < B_*T2_
    int t    = r & (T2_ - 1);           // T2 is a power of two

    // alpha row: 512 floats = 128 f4v; 16 lanes x 8 chunks, 256B/row/instr
    const f4v* arow = (const f4v*)(alpha + (size_t)r * T1_);
    f4v a0 = __builtin_nontemporal_load(&arow[il]);
    f4v a1 = __builtin_nontemporal_load(&arow[il + 16]);
    f4v a2 = __builtin_nontemporal_load(&arow[il + 32]);
    f4v a3 = __builtin_nontemporal_load(&arow[il + 48]);
    f4v a4 = __builtin_nontemporal_load(&arow[il + 64]);
    f4v a5 = __builtin_nontemporal_load(&arow[il + 80]);
    f4v a6 = __builtin_nontemporal_load(&arow[il + 96]);
    f4v a7 = __builtin_nontemporal_load(&arow[il + 112]);

    // mels rows t and t-1 (t==0: load own row, result unused)
    int rm = (t == 0) ? r : (r - 1);
    const f4v* my = (const f4v*)(mels + (size_t)r  * F_);
    const f4v* mx = (const f4v*)(mels + (size_t)rm * F_);
    f4v y0 = my[il * 2], y1 = my[il * 2 + 1];
    f4v x0 = mx[il * 2], x1 = mx[il * 2 + 1];

    float d  = x0.x*y0.x + x0.y*y0.y + x0.z*y0.z + x0.w*y0.w
             + x1.x*y1.x + x1.y*y1.y + x1.z*y1.z + x1.w*y1.w;
    float n0 = x0.x*x0.x + x0.y*x0.y + x0.z*x0.z + x0.w*x0.w
             + x1.x*x1.x + x1.y*x1.y + x1.z*x1.z + x1.w*x1.w;
    float n1 = y0.x*y0.x + y0.y*y0.y + y0.z*y0.z + y0.w*y0.w
             + y1.x*y1.x + y1.y*y1.y + y1.z*y1.z + y1.w*y1.w;

    // psum = sum_s alpha[s]*s ; chunk c covers floats il*4 + 64c .. +3
    float fb = (float)(il * 4);
    float psum;
    psum  = a0.x*(fb      ) + a0.y*(fb +   1.f) + a0.z*(fb +   2.f) + a0.w*(fb +   3.f);
    psum += a1.x*(fb+ 64.f) + a1.y*(fb +  65.f) + a1.z*(fb +  66.f) + a1.w*(fb +  67.f);
    psum += a2.x*(fb+128.f) + a2.y*(fb + 129.f) + a2.z*(fb + 130.f) + a2.w*(fb + 131.f);
    psum += a3.x*(fb+192.f) + a3.y*(fb + 193.f) + a3.z*(fb + 194.f) + a3.w*(fb + 195.f);
    psum += a4.x*(fb+256.f) + a4.y*(fb + 257.f) + a4.z*(fb + 258.f) + a4.w*(fb + 259.f);
    psum += a5.x*(fb+320.f) + a5.y*(fb + 321.f) + a5.z*(fb + 322.f) + a5.w*(fb + 323.f);
    psum += a6.x*(fb+384.f) + a6.y*(fb + 385.f) + a6.z*(fb + 386.f) + a6.w*(fb + 387.f);
    psum += a7.x*(fb+448.f) + a7.y*(fb + 449.f) + a7.z*(fb + 450.f) + a7.w*(fb + 451.f);

    // 16-lane group reduction (xor 8,4,2,1 stays within the group)
    for (int off = 8; off > 0; off >>= 1) {
        psum += __shfl_xor(psum, off, 64);
        d    += __shfl_xor(d,    off, 64);
        n0   += __shfl_xor(n0,   off, 64);
        n1   += __shfl_xor(n1,   off, 64);
    }

    if (il == 0) {
        float a_val;
        if (t == 0) {
            a_val = 1.0f;
        } else {
            float cs = d / (fmaxf(sqrtf(n0), 1e-12f) * fmaxf(sqrtf(n1), 1e-12f));
            a_val = 1.0f / (1.0f + __expf(-STEEP_C * (THRESH_C - cs)));
        }
        act[r]  = a_val * (float)mel_mask[r];
        prop[r] = psum;
    }
}

// --- K2: per batch: eff_delta -> wave-shuffle scan -> rescale -> imv,
//     packed {key, am/Z}, and per-phoneme band bounds.
// v6: bounds via SCATTER from consecutive key pairs (keys monotone -> exactly
// one writer per phoneme, no atomics) instead of 2x 11-level dependent binary
// search chains. Off-by-one at band edges only gates exp(<-90)==0 terms.
__global__ __launch_bounds__(512) void scan_kernel(const float* __restrict__ prop,
                                                   const float* __restrict__ act,
                                                   const int* __restrict__ mel_mask,
                                                   const int* __restrict__ text_mask,
                                                   float* __restrict__ imv_out,
                                                   float2* __restrict__ packed,
                                                   int* __restrict__ bstart,
                                                   int* __restrict__ bend) {
    int b    = blockIdx.x;
    int tid  = threadIdx.x;            // 512 threads, 4 t's each
    int wave = tid >> 6, lane = tid & 63;
    __shared__ float s_imv[T2_];       // later overwritten with search keys
    __shared__ float s_wsum[8];
    __shared__ int   s_am8[8], s_tm8[8];
    __shared__ int   s_tm[T1_];

    const float* pr = prop + (size_t)b * T2_;
    const float* ac = act  + (size_t)b * T2_;
    const int*   mm = mel_mask  + (size_t)b * T2_;
    const int*   tm = text_mask + (size_t)b * T1_;

    int tmv = tm[tid];
    s_tm[tid] = tmv;

    int t0 = tid * 4;
    f4v  pv = *(const f4v*)(pr + t0);
    f4v  av = *(const f4v*)(ac + t0);
    int4 mv = *(const int4*)(mm + t0);
    float prm1 = (tid == 0) ? 0.0f : pr[t0 - 1];

    float d0 = (tid == 0) ? 0.0f : (pv.x - prm1) * av.x;
    float d1 = (pv.y - pv.x) * av.y;
    float d2 = (pv.z - pv.y) * av.z;
    float d3 = (pv.w - pv.z) * av.w;
    d0 = fminf(fmaxf(d0, 0.0f), 1.0f);
    d1 = fminf(fmaxf(d1, 0.0f), 1.0f);
    d2 = fminf(fmaxf(d2, 0.0f), 1.0f);
    d3 = fminf(fmaxf(d3, 0.0f), 1.0f);

    float e[4];
    int   mmv[4];
    e[0] = d0; e[1] = e[0] + d1; e[2] = e[1] + d2; e[3] = e[2] + d3;
    mmv[0] = mv.x; mmv[1] = mv.y; mmv[2] = mv.z; mmv[3] = mv.w;
    float run = e[3];
    int am_local = mv.x + mv.y + mv.z + mv.w;

    int tm_local = tmv;
    for (int off = 32; off > 0; off >>= 1) {
        am_local += __shfl_xor(am_local, off, 64);
        tm_local += __shfl_xor(tm_local, off, 64);
    }
    if (lane == 0) { s_am8[wave] = am_local; s_tm8[wave] = tm_local; }

    // wave-level inclusive scan of per-thread totals
    float v = run;
    for (int off = 1; off < 64; off <<= 1) {
        float u = __shfl_up(v, off, 64);
        if (lane >= off) v += u;
    }
    if (lane == 63) s_wsum[wave] = v;
    __syncthreads();                                    // B1

    float woff = 0.0f;
    for (int w = 0; w < 8; w++) woff += (w < wave) ? s_wsum[w] : 0.0f;
    float excl = woff + v - run;
    {
        f4v sv = { (e[0] + excl) * (float)mmv[0],
                   (e[1] + excl) * (float)mmv[1],
                   (e[2] + excl) * (float)mmv[2],
                   (e[3] + excl) * (float)mmv[3] };
        *(f4v*)(s_imv + t0) = sv;
    }
    __syncthreads();                                    // B2

    int am_total = 0, tm_total = 0;
    for (int w = 0; w < 8; w++) { am_total += s_am8[w]; tm_total += s_tm8[w]; }
    int last_idx = max(am_total - 1, 0);
    float last_val = fmaxf(s_imv[last_idx], 1e-6f);
    float scale = fmaxf((float)tm_total - 1.0f, 0.0f) / last_val;
    __syncthreads();                                    // B3 (everyone read last_val)

    f4v vvv, keyv, rv;
    #pragma unroll
    for (int i = 0; i < 4; i++) {
        int t = t0 + i;
        int valid = mmv[i];
        float vv = s_imv[t] * scale * (float)valid;
        vvv[i] = vv;
        // softmax denominator: 6-term band around floor(vv); excluded terms < 1e-39
        int c = (int)floorf(vv);
        float Z = 0.0f;
        for (int s = c - 2; s <= c + 3; s++) {
            if (s >= 0 && s < T1_ && s_tm[s]) {
                float dd = vv - (float)s;
                Z += __expf(-DELTA_C * dd * dd);
            }
        }
        Z = fmaxf(Z, 1e-30f);
        keyv[i] = valid ? vv : 3.0e4f;                  // monotone past masked tail
        rv[i]   = valid ? (1.0f / Z) : 0.0f;            // r = am/Z
    }
    *(f4v*)(imv_out + (size_t)b * T2_ + t0) = vvv;
    {
        f4v p01 = { keyv[0], rv[0], keyv[1], rv[1] };
        f4v p23 = { keyv[2], rv[2], keyv[3], rv[3] };
        f4v* pko = (f4v*)(packed + (size_t)b * T2_ + t0);
        pko[0] = p01;
        pko[1] = p23;
        f4v* sk = (f4v*)(s_imv + t0);
        *sk = keyv;                                     // keys for kprev read
    }
    __syncthreads();                                    // B4

    // scatter band bounds from consecutive key pairs.
    //   start[s] = lower_bound(key >= s-3): t answers iff s in (k0+3, k1+3]
    //   end[s]   = upper_bound(key >  s+3): t answers iff s in [k0-3, k1-3)
    // keys monotone -> intervals tile -> exactly one writer per s.
    {
        int* bs = bstart + (size_t)b * T1_;
        int* be = bend   + (size_t)b * T1_;
        float kprev = (tid == 0) ? -100.0f : s_imv[t0 - 1];
        #pragma unroll
        for (int i = 0; i < 4; i++) {
            float k0 = fmaxf((i == 0) ? kprev : keyv[i - 1], -100.0f);
            float k1 = keyv[i];
            int t = t0 + i;
            int slo = (int)floorf(k0 + 3.0f) + 1; if (slo < 0) slo = 0;
            int shi = (int)floorf(k1 + 3.0f);     if (shi > T1_ - 1) shi = T1_ - 1;
            for (int s = slo; s <= shi; s++) bs[s] = t;
            slo = (int)ceilf(k0 - 3.0f);          if (slo < 0) slo = 0;
            shi = (int)ceilf(k1 - 3.0f) - 1;      if (shi > T1_ - 1) shi = T1_ - 1;
            for (int s = slo; s <= shi; s++) be[s] = t;
        }
        if (tid == 511) {   // virtual pair (key[T2-1], +inf) at t = T2
            float k0 = fmaxf(keyv[3], -100.0f);
            int slo = (int)floorf(k0 + 3.0f) + 1; if (slo < 0) slo = 0;
            for (int s = slo; s <= T1_ - 1; s++) bs[s] = T2_;
            slo = (int)ceilf(k0 - 3.0f);          if (slo < 0) slo = 0;
            for (int s = slo; s <= T1_ - 1; s++) be[s] = T2_;
        }
    }
}

// --- K3 v6: one wave per 4 adjacent phonemes (bands overlap ~7/9 -> -36%
// frame-visits vs pairs). Wave split into two 32-lane halves, each owning one
// frame with a float4 load; 4 exps/frame/half; 20-shuffle cross-half combine.
// Out-of-band extra terms are exp(<-90) == 0 in fp32, so joint accumulation is exact.
__global__ __launch_bounds__(256) void pool_kernel(const float* __restrict__ mels,
                                                   const int* __restrict__ text_mask,
                                                   const float2* __restrict__ packed,
                                                   const int* __restrict__ bstart,
                                                   const int* __restrict__ bend,
                                                   float* __restrict__ aligned,
                                                   float* __restrict__ dur) {
    int wid  = (int)((blockIdx.x * blockDim.x + threadIdx.x) >> 6);
    int lane = threadIdx.x & 63;
    if (wid >= B_ * (T1_ / 4)) return;
    int b = wid >> 7, s0 = (wid & 127) * 4;   // 128 quads per batch
    int half = lane >> 5, hl = lane & 31;
    float fs0 = (float)s0, fs1 = fs0 + 1.0f, fs2 = fs0 + 2.0f, fs3 = fs0 + 3.0f;

    const float2* pk   = packed + (size_t)b * T2_;
    const f4v*    mel4 = (const f4v*)(mels + (size_t)b * T2_ * F_);
    int t_lo = bstart[(size_t)b * T1_ + s0];
    int t_hi = bend  [(size_t)b * T1_ + s0 + 3];   // covers all 4 bands (monotone)

    float ax0 = 0.f, ay0 = 0.f, az0 = 0.f, aw0 = 0.f, g0s = 0.f;
    float ax1 = 0.f, ay1 = 0.f, az1 = 0.f, aw1 = 0.f, g1s = 0.f;
    float ax2 = 0.f, ay2 = 0.f, az2 = 0.f, aw2 = 0.f, g2s = 0.f;
    float ax3 = 0.f, ay3 = 0.f, az3 = 0.f, aw3 = 0.f, g3s = 0.f;
    for (int t = t_lo; t < t_hi; t += 2) {
        int  tl = t + half;                 // half0 -> t, half1 -> t+1
        bool on = tl < t_hi;
        int  ts = on ? tl : t;              // safe in-band index
        float2 p = pk[ts];
        f4v    m = mel4[(size_t)ts * 32 + hl];
        float e0 = p.x - fs0, e1 = p.x - fs1, e2 = p.x - fs2, e3 = p.x - fs3;
        float g0 = on ? __expf(-DELTA_C * e0 * e0) * p.y : 0.0f;
        float g1 = on ? __expf(-DELTA_C * e1 * e1) * p.y : 0.0f;
        float g2 = on ? __expf(-DELTA_C * e2 * e2) * p.y : 0.0f;
        float g3 = on ? __expf(-DELTA_C * e3 * e3) * p.y : 0.0f;
        g0s += g0; g1s += g1; g2s += g2; g3s += g3;
        ax0 += g0 * m.x; ay0 += g0 * m.y; az0 += g0 * m.z; aw0 += g0 * m.w;
        ax1 += g1 * m.x; ay1 += g1 * m.y; az1 += g1 * m.z; aw1 += g1 * m.w;
        ax2 += g2 * m.x; ay2 += g2 * m.y; az2 += g2 * m.z; aw2 += g2 * m.w;
        ax3 += g3 * m.x; ay3 += g3 * m.y; az3 += g3 * m.z; aw3 += g3 * m.w;
    }

    // cross-half combine: both halves end with full sums
    g0s += __shfl_xor(g0s, 32, 64);  g1s += __shfl_xor(g1s, 32, 64);
    g2s += __shfl_xor(g2s, 32, 64);  g3s += __shfl_xor(g3s, 32, 64);
    ax0 += __shfl_xor(ax0, 32, 64);  ay0 += __shfl_xor(ay0, 32, 64);
    az0 += __shfl_xor(az0, 32, 64);  aw0 += __shfl_xor(aw0, 32, 64);
    ax1 += __shfl_xor(ax1, 32, 64);  ay1 += __shfl_xor(ay1, 32, 64);
    az1 += __shfl_xor(az1, 32, 64);  aw1 += __shfl_xor(aw1, 32, 64);
    ax2 += __shfl_xor(ax2, 32, 64);  ay2 += __shfl_xor(ay2, 32, 64);
    az2 += __shfl_xor(az2, 32, 64);  aw2 += __shfl_xor(aw2, 32, 64);
    ax3 += __shfl_xor(ax3, 32, 64);  ay3 += __shfl_xor(ay3, 32, 64);
    az3 += __shfl_xor(az3, 32, 64);  aw3 += __shfl_xor(aw3, 32, 64);

    int4 tmq = *(const int4*)(text_mask + (size_t)b * T1_ + s0);
    float tm0 = (float)tmq.x, tm1 = (float)tmq.y, tm2 = (float)tmq.z, tm3 = (float)tmq.w;
    float inv0 = tm0 / (g0s + EPS_C);
    float inv1 = tm1 / (g1s + EPS_C);
    float inv2 = tm2 / (g2s + EPS_C);
    float inv3 = tm3 / (g3s + EPS_C);

    // half h writes phoneme rows s0+2h, s0+2h+1: contiguous 1KB per half
    f4v oA, oB;
    if (half == 0) {
        oA.x = ax0 * inv0; oA.y = ay0 * inv0; oA.z = az0 * inv0; oA.w = aw0 * inv0;
        oB.x = ax1 * inv1; oB.y = ay1 * inv1; oB.z = az1 * inv1; oB.w = aw1 * inv1;
    } else {
        oA.x = ax2 * inv2; oA.y = ay2 * inv2; oA.z = az2 * inv2; oA.w = aw2 * inv2;
        oB.x = ax3 * inv3; oB.y = ay3 * inv3; oB.z = az3 * inv3; oB.w = aw3 * inv3;
    }
    float* base = aligned + ((size_t)b * T1_ + s0 + 2 * half) * F_;
    ((f4v*)base)[hl] = oA;
    ((f4v*)(base + F_))[hl] = oB;
    if (lane == 0) {
        f4v dv = { g0s * tm0, g1s * tm1, g2s * tm2, g3s * tm3 };
        *(f4v*)(dur + (size_t)b * T1_ + s0) = dv;
    }
}

extern "C" void kernel_launch(void* const* d_in, const int* in_sizes, int n_in,
                              void* d_out, int out_size, void* d_ws, size_t ws_size,
                              hipStream_t stream) {
    const float* mels      = (const float*)d_in[0];
    const float* alpha     = (const float*)d_in[1];
    const int*   mel_mask  = (const int*)d_in[2];
    const int*   text_mask = (const int*)d_in[3];

    float* out     = (float*)d_out;
    float* aligned = out;                                   // B*T1*F
    float* dur     = out + (size_t)B_ * T1_ * F_;           // B*T1
    float* imv     = dur + (size_t)B_ * T1_;                // B*T2

    float*  ws     = (float*)d_ws;
    float*  act    = ws;                                    // B*T2
    float*  prop   = ws + (size_t)B_ * T2_;                 // B*T2
    float2* packed = (float2*)(ws + 2 * (size_t)B_ * T2_);  // B*T2 float2
    int*    bstart = (int*)(ws + 4 * (size_t)B_ * T2_);     // B*T1
    int*    bend   = bstart + (size_t)B_ * T1_;             // B*T1

    actprop_kernel<<<(B_ * T2_) / 16, dim3(256), 0, stream>>>(mels, alpha, mel_mask, act, prop);
    scan_kernel   <<<B_,              dim3(512), 0, stream>>>(prop, act, mel_mask, text_mask, imv, packed, bstart, bend);
    pool_kernel   <<<(B_ * (T1_ / 4)) / 4, dim3(256), 0, stream>>>(mels, text_mask, packed, bstart, bend, aligned, dur);
}